// Round 6
// baseline (412.480 us; speedup 1.0000x reference)
//
#include <hip/hip_runtime.h>
#include <stdint.h>

// ---------------------------------------------------------------------------
// HistoryEmbTable: emb.at[push_idx].set(x) then gather emb[pull_idx].
// Last push (highest i) wins on duplicate push indices.
//
// Round-6: every pass was bound by random 64B-line traffic (~2.7 TB/s) into
// side structures too big for a 4MB per-XCD L2 (and thrashed by the emb
// stream). Fix: XCD-shard everything by hash-top-3-bits, pin work with
// blockIdx%8, and make per-XCD slices tiny:
//   bitmap  2^26 bits = 8MB  -> 1MB slice/XCD   (pulled-key filter, hashed)
//   table   2^20 x 8B = 8MB  -> 1MB sub-table/XCD (lf ~0.45 incl. false-pass)
// Pulls/pushes are first scattered into 8 shard runs with LDS-binned
// chunk-coalesced writes (no sub-line scatter). Pull writes staging in
// bucket order; dest[j] (recorded at scatter) unpermutes at the end.
// Only remaining random-global traffic: the emb gathers themselves.
//
// Table slot (u64) = ((key+1)<<32) | (pos+1); 0 = empty. CAS claims, and
// atomicMax on key-match (high bits equal -> max over pos) = last-write-wins.
// Nondeterministic run order is fine: winner is max-pos (order-free) and
// out[j] reads the slot its own j was assigned.
// ---------------------------------------------------------------------------

typedef unsigned long long u64;
typedef unsigned u32;

#define NSH      8
#define BLK      256
#define VPT      8                 // items/thread in scatter
#define CHUNK    (BLK * VPT)       // 2048
#define BM_WORDS (1u << 21)        // 2^26 bits = 8MB
#define SUB_BITS 17
#define SUB_SLOTS (1u << SUB_BITS)
#define SUB_MASK (SUB_SLOTS - 1u)
#define CPAD     16                // ints per cursor (64B)

__device__ __forceinline__ u32 hashk(int key) { return (u32)key * 2654435761u; }

// ---- K1/K2: LDS-binned scatter into 8 shard runs ----
template <bool IS_PUSH>
__global__ __launch_bounds__(BLK)
void scatter_kernel(const int* __restrict__ idx, int n,
                    int* __restrict__ cursors,      // [NSH*CPAD]
                    u64* __restrict__ push_runs,    // [NSH*cap] (push)
                    int* __restrict__ pull_keys,    // [NSH*cap] (pull)
                    int* __restrict__ dest,         // [n]       (pull)
                    int cap) {
    __shared__ u64 buf[CHUNK];
    __shared__ int cnt[NSH], lbase[NSH], gbase[NSH];
    int t = threadIdx.x;
    if (t < NSH) cnt[t] = 0;
    __syncthreads();
    int base = blockIdx.x * CHUNK;
    int key_r[VPT], shard_r[VPT], pos_r[VPT];
    #pragma unroll
    for (int e = 0; e < VPT; ++e) {
        int i = base + e * BLK + t;            // coalesced
        if (i < n) {
            int key = idx[i];
            int s = hashk(key) >> 29;
            key_r[e] = key; shard_r[e] = s;
            pos_r[e] = atomicAdd(&cnt[s], 1);  // within-block rank per shard
        } else shard_r[e] = -1;
    }
    __syncthreads();
    if (t == 0) {
        int acc = 0;
        #pragma unroll
        for (int s = 0; s < NSH; ++s) { lbase[s] = acc; acc += cnt[s]; }
    }
    __syncthreads();
    if (t < NSH && cnt[t] > 0) gbase[t] = atomicAdd(&cursors[t * CPAD], cnt[t]);
    __syncthreads();
    #pragma unroll
    for (int e = 0; e < VPT; ++e) {
        if (shard_r[e] >= 0) {
            int i = base + e * BLK + t;
            buf[lbase[shard_r[e]] + pos_r[e]] =
                ((u64)(u32)key_r[e] << 32) | (u32)i;   // key | original index
        }
    }
    __syncthreads();
    int total = lbase[NSH - 1] + cnt[NSH - 1];
    for (int q = t; q < total; q += BLK) {             // segment-coalesced copy-out
        u64 packed = buf[q];
        int key = (int)(packed >> 32);
        int s = hashk(key) >> 29;
        int gp = s * cap + gbase[s] + (q - lbase[s]);
        if (IS_PUSH) {
            push_runs[gp] = packed;                    // key | push pos
        } else {
            pull_keys[gp] = key;
            dest[(u32)packed] = gp;                    // dest[j] = staging slot
        }
    }
}

// ---- K3: bitmap of pulled keys (hash-indexed, shard-local slice) ----
__global__ __launch_bounds__(BLK)
void bitmap_kernel(const int* __restrict__ pull_keys,
                   const int* __restrict__ lens,
                   u32* __restrict__ bitmap, int cap) {
    int s = blockIdx.x & (NSH - 1);
    int tb = blockIdx.x >> 3, nb = gridDim.x >> 3;
    int len = lens[s * CPAD];
    const int* keys = pull_keys + (size_t)s * cap;
    for (int i = tb * BLK + threadIdx.x; i < len; i += nb * BLK) {
        u32 idx26 = hashk(keys[i]) >> 6;               // top3 = shard -> slice
        atomicOr(&bitmap[idx26 >> 5], 1u << (idx26 & 31));
    }
}

// ---- K4: filtered insert into shard sub-table ----
__global__ __launch_bounds__(BLK)
void insert_kernel(const u64* __restrict__ push_runs,
                   const int* __restrict__ lens,
                   const u32* __restrict__ bitmap,
                   u64* __restrict__ table, int cap) {
    int s = blockIdx.x & (NSH - 1);
    int tb = blockIdx.x >> 3, nb = gridDim.x >> 3;
    int len = lens[s * CPAD];
    const u64* run = push_runs + (size_t)s * cap;
    u64* sub = table + ((size_t)s << SUB_BITS);
    for (int i = tb * BLK + threadIdx.x; i < len; i += nb * BLK) {
        u64 packed = run[i];
        int key = (int)(packed >> 32);
        u32 h = hashk(key);
        u32 idx26 = h >> 6;
        if (!((bitmap[idx26 >> 5] >> (idx26 & 31)) & 1u)) continue;
        u64 desired = ((u64)(u32)(key + 1) << 32) | ((u32)packed + 1u);
        u32 slot = (h >> 12) & SUB_MASK;
        for (;;) {
            u64 prev = atomicCAS(&sub[slot], 0ull, desired);
            if (prev == 0ull) break;
            if ((prev >> 32) == (u32)(key + 1)) { atomicMax(&sub[slot], desired); break; }
            slot = (slot + 1) & SUB_MASK;
        }
    }
}

// ---- K5: pull — probe local sub-table + gather emb, write staging ----
__global__ __launch_bounds__(BLK)
void pull_kernel(const int* __restrict__ pull_keys,
                 const int* __restrict__ lens,
                 const u64* __restrict__ table,
                 const float* __restrict__ x,
                 const float* __restrict__ emb,
                 float* __restrict__ staging, int cap) {
    int s = blockIdx.x & (NSH - 1);
    int tb = blockIdx.x >> 3, nb = gridDim.x >> 3;
    int len = lens[s * CPAD];
    const int* keys = pull_keys + (size_t)s * cap;
    const u64* sub = table + ((size_t)s << SUB_BITS);
    float* stg = staging + (size_t)s * cap;
    for (int i = (tb * BLK + threadIdx.x) * 4; i < len; i += nb * BLK * 4) {
        int m = len - i; if (m > 4) m = 4;
        int k[4];
        if (m == 4) { int4 v = *(const int4*)(keys + i); k[0]=v.x; k[1]=v.y; k[2]=v.z; k[3]=v.w; }
        else for (int e = 0; e < m; ++e) k[e] = keys[i + e];
        float g[4]; u32 sl[4]; u64 tv[4];
        for (int e = 0; e < m; ++e) g[e] = emb[k[e]];              // random HBM
        for (int e = 0; e < m; ++e) { sl[e] = (hashk(k[e]) >> 12) & SUB_MASK;
                                      tv[e] = sub[sl[e]]; }        // L2-local
        float r[4];
        for (int e = 0; e < m; ++e) {
            u64 cur = tv[e]; u32 slot = sl[e]; float v = g[e];
            while (cur != 0ull) {
                if ((cur >> 32) == (u32)(k[e] + 1)) { v = x[(u32)cur - 1u]; break; }
                slot = (slot + 1) & SUB_MASK;
                cur = sub[slot];
            }
            r[e] = v;
        }
        if (m == 4) *(float4*)(stg + i) = make_float4(r[0], r[1], r[2], r[3]);
        else for (int e = 0; e < m; ++e) stg[i + e] = r[e];
    }
}

// ---- K6: unpermute ----
__global__ __launch_bounds__(BLK)
void unpermute_kernel(const int* __restrict__ dest,
                      const float* __restrict__ staging,
                      float* __restrict__ out, int n) {
    int j0 = (blockIdx.x * BLK + threadIdx.x) * 4;
    if (j0 + 4 <= n) {
        int4 d = *(const int4*)(dest + j0);
        float4 o = make_float4(staging[d.x], staging[d.y], staging[d.z], staging[d.w]);
        *(float4*)(out + j0) = o;
    } else {
        for (int j = j0; j < n; ++j) out[j] = staging[dest[j]];
    }
}

extern "C" void kernel_launch(void* const* d_in, const int* in_sizes, int n_in,
                              void* d_out, int out_size, void* d_ws, size_t ws_size,
                              hipStream_t stream) {
    const float* emb      = (const float*)d_in[0];
    const float* x        = (const float*)d_in[1];
    const int*   push_idx = (const int*)d_in[2];
    const int*   pull_idx = (const int*)d_in[3];
    float* out = (float*)d_out;

    const int n_push = in_sizes[2];
    const int n_pull = in_sizes[3];
    int n_max = n_push > n_pull ? n_push : n_pull;
    // per-shard run capacity: expected n/8, +25% slack, 256-aligned
    int cap = ((n_max / NSH + n_max / (NSH * 4)) + 255) & ~255;

    // ws layout: [bitmap 8MB][table 8MB][cursors 2x][push_runs][pull_keys]
    //            [staging][dest]   (first 3 regions = one contiguous memset)
    char* p = (char*)d_ws;
    u32* bitmap   = (u32*)p;                 p += (size_t)BM_WORDS * 4;
    u64* table    = (u64*)p;                 p += ((size_t)NSH << SUB_BITS) * 8;
    int* cur_push = (int*)p;                 p += NSH * CPAD * 4;
    int* cur_pull = (int*)p;                 p += NSH * CPAD * 4;
    size_t zero_bytes = (size_t)(p - (char*)d_ws);
    u64* push_runs = (u64*)p;                p += (size_t)NSH * cap * 8;
    int* pull_keys = (int*)p;                p += (size_t)NSH * cap * 4;
    float* staging = (float*)p;              p += (size_t)NSH * cap * 4;
    int* dest      = (int*)p;                p += (size_t)n_pull * 4;

    hipMemsetAsync(d_ws, 0, zero_bytes, stream);

    int scat_push_grid = (n_push + CHUNK - 1) / CHUNK;
    int scat_pull_grid = (n_pull + CHUNK - 1) / CHUNK;
    const int PIN_GRID = 2048;                      // multiple of 8
    scatter_kernel<false><<<scat_pull_grid, BLK, 0, stream>>>(
        pull_idx, n_pull, cur_pull, nullptr, pull_keys, dest, cap);
    scatter_kernel<true><<<scat_push_grid, BLK, 0, stream>>>(
        push_idx, n_push, cur_push, push_runs, nullptr, nullptr, cap);
    bitmap_kernel<<<PIN_GRID, BLK, 0, stream>>>(pull_keys, cur_pull, bitmap, cap);
    insert_kernel<<<PIN_GRID, BLK, 0, stream>>>(push_runs, cur_push, bitmap, table, cap);
    pull_kernel<<<PIN_GRID, BLK, 0, stream>>>(pull_keys, cur_pull, table, x, emb,
                                              staging, cap);
    unpermute_kernel<<<(n_pull + BLK * 4 - 1) / (BLK * 4), BLK, 0, stream>>>(
        dest, staging, out, n_pull);
}

// Round 7
// 384.030 us; speedup vs baseline: 1.0741x; 1.0741x over previous
//
#include <hip/hip_runtime.h>
#include <stdint.h>

// ---------------------------------------------------------------------------
// HistoryEmbTable: emb.at[push_idx].set(x) then gather emb[pull_idx].
// Last push (highest i) wins on duplicate push indices.
//
// Round-7: measured laws from rounds 1-6: random global ATOMICS run at only
// ~25G/s chip-wide (op-rate-bound: batching AND sharding both no-ops), and
// random 64B-line reads at ~2.8TB/s. So eliminate ALL 4M-scale global
// atomics and make the emb gather window-local:
//   bucket = key>>17 (512 buckets, 512KB emb window each -> L2-resident)
//   K1/K2: LDS-staged 512-bin scatter of (key,pos)/(key,j). Items are ranked
//          via LDS atomics, copied out bin-contiguously (~70B segments), and
//          only ~512 cursor atomics/block hit global (250K total, not 4M).
//   K3:    per-bucket exact last-write-wins hash built in LDS (16K x u64,
//          LDS CAS/max - cheap), probe pulls, gather emb inside the 512KB
//          window (fetched ~once, near-streaming), write staging coalesced.
//   K4:    out[j] = staging[dest[j]]  (dest recorded in K2; staging 25MB->L3)
// Winner = max push pos (order-free) and each j reads its own staging slot,
// so output is deterministic despite nondeterministic scatter order.
// ---------------------------------------------------------------------------

typedef unsigned long long u64;
typedef unsigned u32;

#define NB     512              // buckets
#define BSHIFT 17               // bucket = key >> 17 (keys < 2^26)
#define BLK    256
#define VPT    16
#define CHUNK  (BLK * VPT)      // 4096 items per scatter block
#define CAP    12288            // per-bucket run capacity (mean 8734, +38 sigma)
#define CPAD   16               // ints per cursor (64B line)
#define LSLOTS 16384            // LDS hash slots (128KB)
#define LMASK  (LSLOTS - 1)

__device__ __forceinline__ u32 hkey(int key) { return (u32)key * 2654435761u; }

// ---- K1/K2: LDS-binned scatter into 512 bucket runs ----
template <bool IS_PUSH>
__global__ __launch_bounds__(BLK)
void scatter_kernel(const int* __restrict__ idx, int n,
                    int* __restrict__ cursors,      // [NB*CPAD]
                    u64* __restrict__ push_runs,    // [NB*CAP]   (push)
                    int* __restrict__ pull_keys,    // [NB*CAP]   (pull)
                    int* __restrict__ dest) {       // [n]        (pull)
    __shared__ u64 buf[CHUNK];          // 32KB
    __shared__ int cnt[NB];             // 2KB
    __shared__ int basel[NB];           // 2KB
    __shared__ int baseg[NB];           // 2KB
    __shared__ int scan[NB];            // 2KB
    int t = threadIdx.x;
    for (int b = t; b < NB; b += BLK) cnt[b] = 0;
    __syncthreads();

    int base = blockIdx.x * CHUNK;
    int   key_r[VPT];
    short bin_r[VPT];                   // < 512
    short pos_r[VPT];                   // < 4096
    #pragma unroll
    for (int e = 0; e < VPT; ++e) {
        int i = base + e * BLK + t;     // coalesced index load
        if (i < n) {
            int key = idx[i];
            int b = key >> BSHIFT;
            key_r[e] = key;
            bin_r[e] = (short)b;
            pos_r[e] = (short)atomicAdd(&cnt[b], 1);   // LDS atomic (cheap)
        } else bin_r[e] = -1;
    }
    __syncthreads();

    // exclusive scan of cnt -> basel (Hillis-Steele, 2 elems/thread)
    scan[t] = cnt[t]; scan[t + BLK] = cnt[t + BLK];
    __syncthreads();
    for (int d = 1; d < NB; d <<= 1) {
        int a0 = (t       >= d) ? scan[t       - d] : 0;
        int a1 = (t + BLK >= d) ? scan[t + BLK - d] : 0;
        __syncthreads();
        scan[t] += a0; scan[t + BLK] += a1;
        __syncthreads();
    }
    basel[t]       = scan[t]       - cnt[t];
    basel[t + BLK] = scan[t + BLK] - cnt[t + BLK];
    __syncthreads();

    // reserve global run space: ~512 global atomics per block (not 4096)
    for (int b = t; b < NB; b += BLK)
        if (cnt[b] > 0) baseg[b] = atomicAdd(&cursors[b * CPAD], cnt[b]);

    // stage items into LDS, bin-grouped
    #pragma unroll
    for (int e = 0; e < VPT; ++e) {
        if (bin_r[e] >= 0) {
            int i = base + e * BLK + t;
            buf[basel[bin_r[e]] + pos_r[e]] =
                ((u64)(u32)key_r[e] << 32) | (u32)i;    // key | original index
        }
    }
    __syncthreads();

    // copy out: consecutive threads -> consecutive buf slots -> bin-contiguous
    int total = scan[NB - 1];
    for (int q = t; q < total; q += BLK) {
        u64 packed = buf[q];
        int key = (int)(packed >> 32);
        int b = key >> BSHIFT;
        int r = baseg[b] + (q - basel[b]);
        if (r < CAP) {                                  // overflow guard (P~0)
            int gp = b * CAP + r;
            if (IS_PUSH) {
                push_runs[gp] = packed;                 // key | push pos
            } else {
                pull_keys[gp] = key;
                dest[(u32)packed] = gp;                 // dest[j] = staging slot
            }
        }
    }
}

// ---- K3: per-bucket LDS-exact match + window-local emb gather ----
__global__ __launch_bounds__(BLK)
void match_kernel(const u64* __restrict__ push_runs,
                  const int* __restrict__ pull_keys,
                  const int* __restrict__ cur_push,
                  const int* __restrict__ cur_pull,
                  const float* __restrict__ x,
                  const float* __restrict__ emb,
                  float* __restrict__ staging) {
    __shared__ u64 tbl[LSLOTS];   // 128KB
    int b = blockIdx.x;
    int np = cur_push[b * CPAD]; np = np < CAP ? np : CAP;
    int nl = cur_pull[b * CPAD]; nl = nl < CAP ? nl : CAP;
    for (int i = threadIdx.x; i < LSLOTS; i += BLK) tbl[i] = 0ull;
    __syncthreads();

    // build exact last-write-wins hash of this bucket's pushes (LDS atomics)
    const u64* prun = push_runs + (size_t)b * CAP;
    for (int i = threadIdx.x; i < np; i += BLK) {
        u64 packed = prun[i];
        u32 key1 = (u32)(packed >> 32) + 1u;
        u64 want = ((u64)key1 << 32) | ((u32)packed + 1u);   // (key+1)|(pos+1)
        u32 s = (hkey((int)(packed >> 32)) >> 18) & LMASK;
        for (;;) {
            u64 prev = atomicCAS(&tbl[s], 0ull, want);
            if (prev == 0ull) break;                          // claimed
            if ((prev >> 32) == key1) { atomicMax(&tbl[s], want); break; }
            s = (s + 1) & LMASK;
        }
    }
    __syncthreads();

    // probe pulls; emb gather stays inside this bucket's 512KB window
    const int* lkeys = pull_keys + (size_t)b * CAP;
    float* stg = staging + (size_t)b * CAP;
    for (int i = threadIdx.x; i < nl; i += BLK) {
        int key = lkeys[i];
        u32 key1 = (u32)key + 1u;
        u32 s = (hkey(key) >> 18) & LMASK;
        float v;
        for (;;) {
            u64 cur = tbl[s];
            if (cur == 0ull) { v = emb[key]; break; }         // not pushed
            if ((cur >> 32) == key1) { v = x[(u32)cur - 1u]; break; }
            s = (s + 1) & LMASK;
        }
        stg[i] = v;                                           // coalesced
    }
}

// ---- K4: unpermute ----
__global__ __launch_bounds__(BLK)
void unpermute_kernel(const int* __restrict__ dest,
                      const float* __restrict__ staging,
                      float* __restrict__ out, int n) {
    int j0 = (blockIdx.x * BLK + threadIdx.x) * 4;
    if (j0 + 4 <= n) {
        int4 d = *(const int4*)(dest + j0);
        *(float4*)(out + j0) =
            make_float4(staging[d.x], staging[d.y], staging[d.z], staging[d.w]);
    } else {
        for (int j = j0; j < n; ++j) out[j] = staging[dest[j]];
    }
}

extern "C" void kernel_launch(void* const* d_in, const int* in_sizes, int n_in,
                              void* d_out, int out_size, void* d_ws, size_t ws_size,
                              hipStream_t stream) {
    const float* emb      = (const float*)d_in[0];
    const float* x        = (const float*)d_in[1];
    const int*   push_idx = (const int*)d_in[2];
    const int*   pull_idx = (const int*)d_in[3];
    float* out = (float*)d_out;

    const int n_push = in_sizes[2];
    const int n_pull = in_sizes[3];

    // ws layout: [cur_push][cur_pull] (zeroed) [push_runs][pull_keys][staging][dest]
    char* p = (char*)d_ws;
    int* cur_push = (int*)p;                  p += (size_t)NB * CPAD * 4;
    int* cur_pull = (int*)p;                  p += (size_t)NB * CPAD * 4;
    size_t zero_bytes = (size_t)(p - (char*)d_ws);
    u64*   push_runs = (u64*)p;               p += (size_t)NB * CAP * 8;
    int*   pull_keys = (int*)p;               p += (size_t)NB * CAP * 4;
    float* staging   = (float*)p;             p += (size_t)NB * CAP * 4;
    int*   dest      = (int*)p;               p += (size_t)n_pull * 4;

    hipMemsetAsync(d_ws, 0, zero_bytes, stream);   // 64KB only

    int grid_push = (n_push + CHUNK - 1) / CHUNK;
    int grid_pull = (n_pull + CHUNK - 1) / CHUNK;
    scatter_kernel<true><<<grid_push, BLK, 0, stream>>>(
        push_idx, n_push, cur_push, push_runs, nullptr, nullptr);
    scatter_kernel<false><<<grid_pull, BLK, 0, stream>>>(
        pull_idx, n_pull, cur_pull, nullptr, pull_keys, dest);
    match_kernel<<<NB, BLK, 0, stream>>>(push_runs, pull_keys,
                                         cur_push, cur_pull, x, emb, staging);
    unpermute_kernel<<<(n_pull + BLK * 4 - 1) / (BLK * 4), BLK, 0, stream>>>(
        dest, staging, out, n_pull);
}

// Round 8
// 243.928 us; speedup vs baseline: 1.6910x; 1.5744x over previous
//
#include <hip/hip_runtime.h>
#include <stdint.h>

// ---------------------------------------------------------------------------
// HistoryEmbTable: emb.at[push_idx].set(x) then gather emb[pull_idx].
// Last push (highest i) wins on duplicate push indices.
//
// Partition pipeline (round-7) with the match occupancy fix (round-8):
//   bucket = key>>17 (512 buckets, 512KB emb window each)
//   K1/K2: LDS-staged 512-bin scatter of (key,pos)/(key,j); LDS-atomic
//          ranking, bin-contiguous copy-out, ~512 global cursor atomics/block.
//   K3:    per-bucket exact last-write-wins hash in LDS (16K x u64 = 128KB).
//          Round-8: BLK=1024 (16 waves/CU instead of 4 -- the 128KB table
//          limits to 1 WG/CU, so waves must come from block size; measured
//          round-7: 9.5% occupancy, 955GB/s, latency-bound) and emb[key]
//          issued BEFORE the LDS probe (chain-break).
//   K4:    out[j] = staging[dest[j]].
// Winner = max push pos (order-free); each j reads its own staging slot, so
// output is deterministic despite nondeterministic scatter order.
// ---------------------------------------------------------------------------

typedef unsigned long long u64;
typedef unsigned u32;

#define NB     512              // buckets
#define BSHIFT 17               // bucket = key >> 17 (keys < 2^26)
#define BLK    256
#define MBLK   1024             // match block: 16 waves
#define VPT    16
#define CHUNK  (BLK * VPT)      // 4096 items per scatter block
#define CAP    12288            // per-bucket run capacity (mean 8734, +38 sigma)
#define CPAD   16               // ints per cursor (64B line)
#define LSLOTS 16384            // LDS hash slots (128KB)
#define LMASK  (LSLOTS - 1)

__device__ __forceinline__ u32 hkey(int key) { return (u32)key * 2654435761u; }

// ---- K1/K2: LDS-binned scatter into 512 bucket runs ----
template <bool IS_PUSH>
__global__ __launch_bounds__(BLK)
void scatter_kernel(const int* __restrict__ idx, int n,
                    int* __restrict__ cursors,      // [NB*CPAD]
                    u64* __restrict__ push_runs,    // [NB*CAP]   (push)
                    int* __restrict__ pull_keys,    // [NB*CAP]   (pull)
                    int* __restrict__ dest) {       // [n]        (pull)
    __shared__ u64 buf[CHUNK];          // 32KB
    __shared__ int cnt[NB];             // 2KB
    __shared__ int basel[NB];           // 2KB
    __shared__ int baseg[NB];           // 2KB
    __shared__ int scan[NB];            // 2KB
    int t = threadIdx.x;
    for (int b = t; b < NB; b += BLK) cnt[b] = 0;
    __syncthreads();

    int base = blockIdx.x * CHUNK;
    int   key_r[VPT];
    short bin_r[VPT];                   // < 512
    short pos_r[VPT];                   // < 4096
    #pragma unroll
    for (int e = 0; e < VPT; ++e) {
        int i = base + e * BLK + t;     // coalesced index load
        if (i < n) {
            int key = idx[i];
            int b = key >> BSHIFT;
            key_r[e] = key;
            bin_r[e] = (short)b;
            pos_r[e] = (short)atomicAdd(&cnt[b], 1);   // LDS atomic (cheap)
        } else bin_r[e] = -1;
    }
    __syncthreads();

    // exclusive scan of cnt -> basel (Hillis-Steele, 2 elems/thread)
    scan[t] = cnt[t]; scan[t + BLK] = cnt[t + BLK];
    __syncthreads();
    for (int d = 1; d < NB; d <<= 1) {
        int a0 = (t       >= d) ? scan[t       - d] : 0;
        int a1 = (t + BLK >= d) ? scan[t + BLK - d] : 0;
        __syncthreads();
        scan[t] += a0; scan[t + BLK] += a1;
        __syncthreads();
    }
    basel[t]       = scan[t]       - cnt[t];
    basel[t + BLK] = scan[t + BLK] - cnt[t + BLK];
    __syncthreads();

    // reserve global run space: ~512 global atomics per block (not 4096)
    for (int b = t; b < NB; b += BLK)
        if (cnt[b] > 0) baseg[b] = atomicAdd(&cursors[b * CPAD], cnt[b]);

    // stage items into LDS, bin-grouped
    #pragma unroll
    for (int e = 0; e < VPT; ++e) {
        if (bin_r[e] >= 0) {
            int i = base + e * BLK + t;
            buf[basel[bin_r[e]] + pos_r[e]] =
                ((u64)(u32)key_r[e] << 32) | (u32)i;    // key | original index
        }
    }
    __syncthreads();

    // copy out: consecutive threads -> consecutive buf slots -> bin-contiguous
    int total = scan[NB - 1];
    for (int q = t; q < total; q += BLK) {
        u64 packed = buf[q];
        int key = (int)(packed >> 32);
        int b = key >> BSHIFT;
        int r = baseg[b] + (q - basel[b]);
        if (r < CAP) {                                  // overflow guard (P~0)
            int gp = b * CAP + r;
            if (IS_PUSH) {
                push_runs[gp] = packed;                 // key | push pos
            } else {
                pull_keys[gp] = key;
                dest[(u32)packed] = gp;                 // dest[j] = staging slot
            }
        }
    }
}

// ---- K3: per-bucket LDS-exact match + window-local emb gather ----
__global__ __launch_bounds__(MBLK)
void match_kernel(const u64* __restrict__ push_runs,
                  const int* __restrict__ pull_keys,
                  const int* __restrict__ cur_push,
                  const int* __restrict__ cur_pull,
                  const float* __restrict__ x,
                  const float* __restrict__ emb,
                  float* __restrict__ staging) {
    __shared__ u64 tbl[LSLOTS];   // 128KB -> 1 WG/CU; waves come from MBLK
    int b = blockIdx.x;
    int np = cur_push[b * CPAD]; np = np < CAP ? np : CAP;
    int nl = cur_pull[b * CPAD]; nl = nl < CAP ? nl : CAP;
    for (int i = threadIdx.x; i < LSLOTS; i += MBLK) tbl[i] = 0ull;
    __syncthreads();

    // build exact last-write-wins hash of this bucket's pushes (LDS atomics)
    const u64* prun = push_runs + (size_t)b * CAP;
    for (int i = threadIdx.x; i < np; i += MBLK) {
        u64 packed = prun[i];
        u32 key1 = (u32)(packed >> 32) + 1u;
        u64 want = ((u64)key1 << 32) | ((u32)packed + 1u);   // (key+1)|(pos+1)
        u32 s = (hkey((int)(packed >> 32)) >> 18) & LMASK;
        for (;;) {
            u64 prev = atomicCAS(&tbl[s], 0ull, want);
            if (prev == 0ull) break;                          // claimed
            if ((prev >> 32) == key1) { atomicMax(&tbl[s], want); break; }
            s = (s + 1) & LMASK;
        }
    }
    __syncthreads();

    // probe pulls; emb issued BEFORE the probe loop (chain-break); window-local
    const int* lkeys = pull_keys + (size_t)b * CAP;
    float* stg = staging + (size_t)b * CAP;
    for (int i = threadIdx.x; i < nl; i += MBLK) {
        int key = lkeys[i];
        float v = emb[key];                                   // in flight now
        u32 key1 = (u32)key + 1u;
        u32 s = (hkey(key) >> 18) & LMASK;
        for (;;) {
            u64 cur = tbl[s];
            if (cur == 0ull) break;                           // not pushed
            if ((cur >> 32) == key1) { v = x[(u32)cur - 1u]; break; }
            s = (s + 1) & LMASK;
        }
        stg[i] = v;                                           // coalesced
    }
}

// ---- K4: unpermute ----
__global__ __launch_bounds__(BLK)
void unpermute_kernel(const int* __restrict__ dest,
                      const float* __restrict__ staging,
                      float* __restrict__ out, int n) {
    int j0 = (blockIdx.x * BLK + threadIdx.x) * 4;
    if (j0 + 4 <= n) {
        int4 d = *(const int4*)(dest + j0);
        *(float4*)(out + j0) =
            make_float4(staging[d.x], staging[d.y], staging[d.z], staging[d.w]);
    } else {
        for (int j = j0; j < n; ++j) out[j] = staging[dest[j]];
    }
}

extern "C" void kernel_launch(void* const* d_in, const int* in_sizes, int n_in,
                              void* d_out, int out_size, void* d_ws, size_t ws_size,
                              hipStream_t stream) {
    const float* emb      = (const float*)d_in[0];
    const float* x        = (const float*)d_in[1];
    const int*   push_idx = (const int*)d_in[2];
    const int*   pull_idx = (const int*)d_in[3];
    float* out = (float*)d_out;

    const int n_push = in_sizes[2];
    const int n_pull = in_sizes[3];

    // ws layout: [cur_push][cur_pull] (zeroed) [push_runs][pull_keys][staging][dest]
    char* p = (char*)d_ws;
    int* cur_push = (int*)p;                  p += (size_t)NB * CPAD * 4;
    int* cur_pull = (int*)p;                  p += (size_t)NB * CPAD * 4;
    size_t zero_bytes = (size_t)(p - (char*)d_ws);
    u64*   push_runs = (u64*)p;               p += (size_t)NB * CAP * 8;
    int*   pull_keys = (int*)p;               p += (size_t)NB * CAP * 4;
    float* staging   = (float*)p;             p += (size_t)NB * CAP * 4;
    int*   dest      = (int*)p;               p += (size_t)n_pull * 4;

    hipMemsetAsync(d_ws, 0, zero_bytes, stream);   // 64KB only

    int grid_push = (n_push + CHUNK - 1) / CHUNK;
    int grid_pull = (n_pull + CHUNK - 1) / CHUNK;
    scatter_kernel<true><<<grid_push, BLK, 0, stream>>>(
        push_idx, n_push, cur_push, push_runs, nullptr, nullptr);
    scatter_kernel<false><<<grid_pull, BLK, 0, stream>>>(
        pull_idx, n_pull, cur_pull, nullptr, pull_keys, dest);
    match_kernel<<<NB, MBLK, 0, stream>>>(push_runs, pull_keys,
                                          cur_push, cur_pull, x, emb, staging);
    unpermute_kernel<<<(n_pull + BLK * 4 - 1) / (BLK * 4), BLK, 0, stream>>>(
        dest, staging, out, n_pull);
}